// Round 1
// baseline (1426.306 us; speedup 1.0000x reference)
//
#include <hip/hip_runtime.h>
#include <hip/hip_bf16.h>
#include <cstdint>

// CrossAttention: out = softmax((XqWq)(XkWk)^T per-token over heads) (XvWv) @ Wo + bo
// N=32768, D=512, H=8, DH=4096.
//
// Round 5: replace 128x128 2-phase GEMM (665 TF, MfmaUtil 28.5%) with the
// 256x256 8-phase template (T2+T3+T4+T5):
//  - BM=BN=256, BK=64, 512 thr (8 waves, 2x4), LDS 128 KiB double-buffered.
//  - per phase: {ds_read subtile || stage 1 half-tile} -> s_barrier ->
//    lgkmcnt(0) -> setprio(1) -> 16 MFMA -> setprio(0) -> [vmcnt(4)] -> s_barrier.
//  - counted vmcnt(4) only at phases 3/7 (loads stay in flight across barriers);
//    staging schedule is fully barrier-protected (each half restaged only after
//    its last reader's phase completed) -> race-free by construction.
//  - XOR k-group swizzle kept: LDS linear dest, inverse-swizzled global source,
//    swizzled ds_read (conflict-free b128).

typedef unsigned short u16;
typedef unsigned int u32;
typedef __bf16 bf16x8 __attribute__((ext_vector_type(8)));
typedef float f32x4 __attribute__((ext_vector_type(4)));

#define DEVI __device__ __forceinline__

DEVI float b2f(u16 u) {
    union { u32 i; float f; } c; c.i = ((u32)u) << 16; return c.f;
}
DEVI u16 f2b(float f) {  // RNE
    union { float f; u32 i; } c; c.f = f;
    return (u16)((c.i + 0x7FFFu + ((c.i >> 16) & 1u)) >> 16);
}

DEVI void async16(const u16* g, u16* l) {
    __builtin_amdgcn_global_load_lds(
        (const __attribute__((address_space(1))) u32*)g,
        (__attribute__((address_space(3))) u32*)l, 16, 0, 0);
}

// ---------------- prep kernels ----------------

__global__ __launch_bounds__(256) void cvt3_bf16(
    const float* __restrict__ a, const float* __restrict__ b,
    const float* __restrict__ c, u16* __restrict__ out, long ostride) {
    const float* in = (blockIdx.z == 0) ? a : (blockIdx.z == 1) ? b : c;
    u16* o = out + (long)blockIdx.z * ostride;
    const int i = blockIdx.x * 256 + threadIdx.x;
    const float4 x = ((const float4*)in)[2 * i];
    const float4 y = ((const float4*)in)[2 * i + 1];
    union { u16 u[8]; uint4 v; } r;
    r.u[0] = f2b(x.x); r.u[1] = f2b(x.y); r.u[2] = f2b(x.z); r.u[3] = f2b(x.w);
    r.u[4] = f2b(y.x); r.u[5] = f2b(y.y); r.u[6] = f2b(y.z); r.u[7] = f2b(y.w);
    ((uint4*)o)[i] = r.v;
}

__global__ void transpose_cvt(const float* __restrict__ in, u16* __restrict__ out,
                              int R, int C) {
    __shared__ float tile[32][33];
    const int c0 = blockIdx.x * 32, r0 = blockIdx.y * 32;
    const int x = threadIdx.x, y = threadIdx.y;
#pragma unroll
    for (int i = 0; i < 4; ++i) {
        const int r = y + i * 8;
        tile[x][r] = in[(long)(r0 + r) * C + c0 + x];
    }
    __syncthreads();
#pragma unroll
    for (int i = 0; i < 4; ++i) {
        const int c = y + i * 8;
        out[(long)(c0 + c) * R + r0 + x] = f2b(tile[c][x]);
    }
}

// ---------------- GEMM: C[M][N] = A[M][K] * BT[N][K]^T (+bias if F32OUT) -------
// 256x256 tile, 8-phase schedule. K multiple of 128 (NT even, >= 4).

#define VM4 asm volatile("s_waitcnt vmcnt(4)" ::: "memory")
#define VM0 asm volatile("s_waitcnt vmcnt(0)" ::: "memory")
#define LGKM0 asm volatile("s_waitcnt lgkmcnt(0)" ::: "memory")
#define NOOP ((void)0)

// stage half h (128 rows) of K-tile t into buf (t&1); 2 x global_load_lds/thread
#define STAGE_A(t, h)                                                     \
    do {                                                                  \
        const u16* _s = pA + (long)(h) * 128 * K + (long)(t) * 64;        \
        u16* _d = As + (((t) & 1) * 16384) + (h) * 8192 + wave * 512;     \
        async16(_s, _d);                                                  \
        async16(_s + 64 * (long)K, _d + 4096);                            \
    } while (0)

#define STAGE_B(t, h)                                                     \
    do {                                                                  \
        const u16* _s = pB + (long)(h) * 128 * K + (long)(t) * 64;        \
        u16* _d = Bs + (((t) & 1) * 16384) + (h) * 8192 + wave * 512;     \
        async16(_s, _d);                                                  \
        async16(_s + 64 * (long)K, _d + 4096);                            \
    } while (0)

// one phase: ds_read quadrant P of buf c (+ all B-frags at P==0), issue STG,
// barrier, drain lgkm, 16 MFMA under setprio, optional vmcnt, barrier.
#define PHASE(c, P, STG, VW)                                                   \
    {                                                                          \
        const u16* _sA = As + (c) * 16384;                                     \
        const u16* _sB = Bs + (c) * 16384;                                     \
        bf16x8 a00 = *(const bf16x8*)(_sA + arow_u + (2 * (P)) * 1024 + s0);   \
        bf16x8 a01 = *(const bf16x8*)(_sA + arow_u + (2 * (P)) * 1024 + s1);   \
        bf16x8 a10 = *(const bf16x8*)(_sA + arow_u + (2 * (P) + 1) * 1024 + s0); \
        bf16x8 a11 = *(const bf16x8*)(_sA + arow_u + (2 * (P) + 1) * 1024 + s1); \
        if ((P) == 0) {                                                        \
            _Pragma("unroll") for (int n = 0; n < 4; ++n) {                    \
                bfr[n][0] = *(const bf16x8*)(_sB + brow_u + n * 1024 + s0);    \
                bfr[n][1] = *(const bf16x8*)(_sB + brow_u + n * 1024 + s1);    \
            }                                                                  \
        }                                                                      \
        STG;                                                                   \
        __builtin_amdgcn_s_barrier();                                          \
        LGKM0;                                                                 \
        __builtin_amdgcn_s_setprio(1);                                         \
        _Pragma("unroll") for (int n = 0; n < 4; ++n) {                        \
            acc[2 * (P)][n] = __builtin_amdgcn_mfma_f32_16x16x32_bf16(         \
                a00, bfr[n][0], acc[2 * (P)][n], 0, 0, 0);                     \
            acc[2 * (P)][n] = __builtin_amdgcn_mfma_f32_16x16x32_bf16(         \
                a01, bfr[n][1], acc[2 * (P)][n], 0, 0, 0);                     \
            acc[2 * (P) + 1][n] = __builtin_amdgcn_mfma_f32_16x16x32_bf16(     \
                a10, bfr[n][0], acc[2 * (P) + 1][n], 0, 0, 0);                 \
            acc[2 * (P) + 1][n] = __builtin_amdgcn_mfma_f32_16x16x32_bf16(     \
                a11, bfr[n][1], acc[2 * (P) + 1][n], 0, 0, 0);                 \
        }                                                                      \
        __builtin_amdgcn_s_setprio(0);                                         \
        VW;                                                                    \
        __builtin_amdgcn_s_barrier();                                          \
    }

template <int F32OUT>
__global__ __launch_bounds__(512, 2) void gemm256(
    const u16* __restrict__ Ab, const u16* __restrict__ Bb,
    void* __restrict__ Cv, const float* __restrict__ bias,
    int M, int N, int K, long sAz, long sBz, long sCz) {
    __shared__ u16 As[2 * 16384];   // 2 bufs x [256 rows][64 k]
    __shared__ u16 Bs[2 * 16384];
    (void)M;
    const int tid = threadIdx.x;
    const int wave = tid >> 6, lane = tid & 63;
    const int z = blockIdx.z;
    const u16* A = Ab + (long)z * sAz;
    const u16* BT = Bb + (long)z * sBz;

    // bijective XCD swizzle over the flattened grid
    int bx, by;
    {
        const int gx = gridDim.x, nwg = gx * gridDim.y;
        const int b = blockIdx.y * gx + blockIdx.x;
        if ((nwg & 7) == 0) {
            const int cpx = nwg >> 3;
            const int w = (b & 7) * cpx + (b >> 3);
            bx = w % gx; by = w / gx;
        } else { bx = blockIdx.x; by = blockIdx.y; }
    }
    const long row0 = (long)by * 256, col0 = (long)bx * 256;

    const int mrow = lane & 15, quad = lane >> 4;
    const int wr = wave >> 2, wc = wave & 3;       // 2 x 4 wave grid
    // swizzled 16B-slot offsets (u16 units) for k-slice 0/1
    const int s0 = ((quad ^ (mrow & 7)) << 3);
    const int s1 = (((4 | quad) ^ (mrow & 7)) << 3);
    const int arow_u = (wr * 128 + mrow) * 64;
    const int brow_u = (wc * 64 + mrow) * 64;

    // staging: thread covers LDS slot s=tid (rows 0-63) and s=tid+512 (rows 64-127)
    // of a half; slot c of row r holds k-group c^(r&7) -> pre-swizzle the source.
    const int sr = tid >> 3;
    const int skg = ((tid & 7) ^ (sr & 7)) << 3;
    const u16* pA = A + (row0 + sr) * (long)K + skg;
    const u16* pB = BT + (col0 + sr) * (long)K + skg;

    f32x4 acc[8][4] = {};
    bf16x8 bfr[4][2];

    const int NT = K >> 6;   // even, >= 4
    const int NI = NT >> 1;

    // prologue: tile0 fully + tile1's B halves; wait tile0 landed (<=4 in flight)
    STAGE_A(0, 0); STAGE_A(0, 1); STAGE_B(0, 0); STAGE_B(0, 1);
    STAGE_B(1, 0); STAGE_B(1, 1);
    VM4;
    __builtin_amdgcn_s_barrier();

#pragma unroll 1
    for (int it = 0; it < NI - 1; ++it) {
        const int t1 = 2 * it + 1;
        // tile 2it (buf0); stage: tile t1's A (buf1, safe), tile t1+1's B (buf0,
        // B consumed at P0, safe)
        PHASE(0, 0, STAGE_A(t1, 0), NOOP);
        PHASE(0, 1, STAGE_A(t1, 1), NOOP);
        PHASE(0, 2, STAGE_B(t1 + 1, 0), NOOP);
        PHASE(0, 3, STAGE_B(t1 + 1, 1), VM4);   // tile t1 fully landed
        // tile t1 (buf1); stage: tile t1+1's A (buf0, prev tile done, safe),
        // tile t1+2's B (buf1, B consumed at P0, safe)
        PHASE(1, 0, STAGE_A(t1 + 1, 0), NOOP);
        PHASE(1, 1, STAGE_A(t1 + 1, 1), NOOP);
        PHASE(1, 2, STAGE_B(t1 + 2, 0), NOOP);
        PHASE(1, 3, STAGE_B(t1 + 2, 1), VM4);   // tile t1+1 fully landed
    }
    {   // tail iteration: tiles NT-2 (buf0), NT-1 (buf1); no prefetch beyond
        const int tl = NT - 1;
        PHASE(0, 0, STAGE_A(tl, 0), NOOP);
        PHASE(0, 1, STAGE_A(tl, 1), NOOP);
        PHASE(0, 2, NOOP, NOOP);
        PHASE(0, 3, NOOP, VM0);                 // tile NT-1 fully landed
        PHASE(1, 0, NOOP, NOOP);
        PHASE(1, 1, NOOP, NOOP);
        PHASE(1, 2, NOOP, NOOP);
        PHASE(1, 3, NOOP, NOOP);
    }

    // epilogue: D[row=(quad*4+rr)][col=mrow] per 16x16 tile (m89/m91 layout)
    const long wrow = row0 + wr * 128;
    const long wcol = col0 + wc * 64;
    if (F32OUT) {
        float* C = (float*)Cv + (long)z * sCz;
        float bv[4];
#pragma unroll
        for (int n = 0; n < 4; ++n) bv[n] = bias[wcol + n * 16 + mrow];
#pragma unroll
        for (int m = 0; m < 8; ++m) {
            const long r = wrow + m * 16 + quad * 4;
#pragma unroll
            for (int n = 0; n < 4; ++n) {
                const long c = wcol + n * 16 + mrow;
#pragma unroll
                for (int rr = 0; rr < 4; ++rr)
                    C[(r + rr) * (long)N + c] = acc[m][n][rr] + bv[n];
            }
        }
    } else {
        u16* C = (u16*)Cv + (long)z * sCz;
#pragma unroll
        for (int m = 0; m < 8; ++m) {
            const long r = wrow + m * 16 + quad * 4;
#pragma unroll
            for (int n = 0; n < 4; ++n) {
                const long c = wcol + n * 16 + mrow;
#pragma unroll
                for (int rr = 0; rr < 4; ++rr)
                    C[(r + rr) * (long)N + c] = f2b(acc[m][n][rr]);
            }
        }
    }
}

#undef PHASE
#undef STAGE_A
#undef STAGE_B

// ---------------- per-token attention over heads ----------------

__global__ __launch_bounds__(256) void attn_kernel(
    const u16* __restrict__ Qg, const u16* __restrict__ Kg,
    const u16* __restrict__ Vg, u16* __restrict__ Og) {
    __shared__ uint4 sQ[512], sK[512], sV[512];
    __shared__ float part[4][64];
    __shared__ float logitS[64];
    __shared__ float probS[64];
    const int t = threadIdx.x;
    const long base = (long)blockIdx.x * 4096;

    const uint4* q4 = (const uint4*)(Qg + base);
    const uint4* k4 = (const uint4*)(Kg + base);
    const uint4* v4 = (const uint4*)(Vg + base);
    sQ[t] = q4[t]; sQ[t + 256] = q4[t + 256];
    sK[t] = k4[t]; sK[t + 256] = k4[t + 256];
    sV[t] = v4[t]; sV[t + 256] = v4[t + 256];
    __syncthreads();

    const u16* Qs = (const u16*)sQ;
    const u16* Ks = (const u16*)sK;
    const u16* Vs = (const u16*)sV;

    {
        const int pr = t & 63, ch = t >> 6;
        const int h = pr >> 3, g = pr & 7;
        const u16* qp = Qs + h * 512 + ch * 128;
        const u16* kp = Ks + g * 512 + ch * 128;
        float s = 0.f;
#pragma unroll
        for (int i = 0; i < 128; ++i) s += b2f(qp[i]) * b2f(kp[i]);
        part[ch][pr] = s;
    }
    __syncthreads();
    if (t < 64) logitS[t] = part[0][t] + part[1][t] + part[2][t] + part[3][t];
    __syncthreads();
    if (t < 8) {
        float m = logitS[t * 8];
#pragma unroll
        for (int g = 1; g < 8; ++g) m = fmaxf(m, logitS[t * 8 + g]);
        float e[8], sum = 0.f;
#pragma unroll
        for (int g = 0; g < 8; ++g) { e[g] = __expf(logitS[t * 8 + g] - m); sum += e[g]; }
        const float inv = 1.f / sum;
#pragma unroll
        for (int g = 0; g < 8; ++g) probS[t * 8 + g] = e[g] * inv;
    }
    __syncthreads();

    const int hh = t >> 5, d0 = (t & 31) * 16;
    float p[8];
#pragma unroll
    for (int g = 0; g < 8; ++g) p[g] = probS[hh * 8 + g];
    float o[16];
#pragma unroll
    for (int j = 0; j < 16; ++j) o[j] = 0.f;
#pragma unroll
    for (int g = 0; g < 8; ++g) {
        const u16* vp = Vs + g * 512 + d0;
#pragma unroll
        for (int j = 0; j < 16; ++j) o[j] += p[g] * b2f(vp[j]);
    }
    union { u16 u[16]; uint4 v[2]; } ob;
#pragma unroll
    for (int j = 0; j < 16; ++j) ob.u[j] = f2b(o[j]);
    uint4* op = (uint4*)(Og + base + hh * 512 + d0);
    op[0] = ob.v[0]; op[1] = ob.v[1];
}

// ---------------- launch ----------------

extern "C" void kernel_launch(void* const* d_in, const int* in_sizes, int n_in,
                              void* d_out, int out_size, void* d_ws, size_t ws_size,
                              hipStream_t stream) {
    const float* Xq = (const float*)d_in[0];
    const float* Xk = (const float*)d_in[1];
    const float* Xv = (const float*)d_in[2];
    const float* Wq = (const float*)d_in[3];
    const float* Wk = (const float*)d_in[4];
    const float* Wv = (const float*)d_in[5];
    const float* Wo = (const float*)d_in[6];
    const float* bo = (const float*)d_in[7];

    const int N = 32768;
    const size_t W = 16777216ull;      // transposed weights
    const size_t AO = 268435456ull;    // full-N attn_out (Plan A)

    int McA = 0;
    for (int m = 8192; m >= 1024; m >>= 1)
        if (W + AO + (size_t)m * 27648ull <= ws_size) { McA = m; break; }

    char* ws = (char*)d_ws;
    u16* WqT = (u16*)(ws);                    // [4096][512] x3 contiguous
    u16* WoT = (u16*)(ws + 12582912ull);      // [512][4096]

    dim3 tb(32, 8);
    transpose_cvt<<<dim3(128, 16), tb, 0, stream>>>(Wq, WqT, 512, 4096);
    transpose_cvt<<<dim3(128, 16), tb, 0, stream>>>(Wk, WqT + 2097152, 512, 4096);
    transpose_cvt<<<dim3(128, 16), tb, 0, stream>>>(Wv, WqT + 4194304, 512, 4096);
    transpose_cvt<<<dim3(16, 128), tb, 0, stream>>>(Wo, WoT, 4096, 512);

    if (McA) {
        // ---- Plan A ----
        const int Mc = McA;
        u16* Ao  = (u16*)(ws + W);
        u16* Xb  = (u16*)(ws + W + AO);           // 3x [Mc][512]
        u16* Qc  = Xb + (size_t)3 * Mc * 512;     // 3x [Mc][4096]
        u16* Kc  = Qc + (size_t)Mc * 4096;
        u16* Vc  = Kc + (size_t)Mc * 4096;
        const dim3 gProj(16, Mc / 256, 3);
        for (int m0 = 0; m0 < N; m0 += Mc) {
            const long xoff = (long)m0 * 512;
            cvt3_bf16<<<dim3(Mc / 4, 1, 3), 256, 0, stream>>>(
                Xq + xoff, Xk + xoff, Xv + xoff, Xb, (long)Mc * 512);
            gemm256<0><<<gProj, 512, 0, stream>>>(Xb, WqT, Qc, nullptr,
                                                  Mc, 4096, 512,
                                                  (long)Mc * 512, 2097152L,
                                                  (long)Mc * 4096);
            attn_kernel<<<Mc, 256, 0, stream>>>(Qc, Kc, Vc, Ao + (long)m0 * 4096);
        }
        gemm256<1><<<dim3(2, 128, 1), 512, 0, stream>>>(
            Ao, WoT, d_out, bo, N, 512, 4096, 0L, 0L, 0L);
    } else {
        // ---- Plan B (streaming) ----
        int Mc = 8192;
        while (Mc > 256 && W + (size_t)Mc * 27648ull > ws_size) Mc >>= 1;
        if (W + (size_t)Mc * 27648ull > ws_size) return;
        u16* Xb = (u16*)(ws + W);
        u16* Qc = Xb + (size_t)3 * Mc * 512;
        u16* Kc = Qc + (size_t)Mc * 4096;
        u16* Vc = Kc + (size_t)Mc * 4096;
        const dim3 gProj(16, Mc / 256, 3);
        const dim3 gOut(2, Mc / 256, 1);
        for (int m0 = 0; m0 < N; m0 += Mc) {
            const long xoff = (long)m0 * 512;
            cvt3_bf16<<<dim3(Mc / 4, 1, 3), 256, 0, stream>>>(
                Xq + xoff, Xk + xoff, Xv + xoff, Xb, (long)Mc * 512);
            gemm256<0><<<gProj, 512, 0, stream>>>(Xb, WqT, Qc, nullptr,
                                                  Mc, 4096, 512,
                                                  (long)Mc * 512, 2097152L,
                                                  (long)Mc * 4096);
            attn_kernel<<<Mc, 256, 0, stream>>>(Qc, Kc, Vc, Qc);
            gemm256<1><<<gOut, 512, 0, stream>>>(Qc, WoT, (float*)d_out + xoff, bo,
                                                 Mc, 512, 4096, 0L, 0L, 0L);
        }
    }
}

// Round 2
// 1352.728 us; speedup vs baseline: 1.0544x; 1.0544x over previous
//
#include <hip/hip_runtime.h>
#include <hip/hip_bf16.h>
#include <cstdint>

// CrossAttention: out = softmax((XqWq)(XkWk)^T per-token over heads) (XvWv) @ Wo + bo
// N=32768, D=512, H=8, DH=4096.
//
// Round 6: vectorize attn_kernel (was scalar ds_read_u16 + scalar cvt — the
// dominant hidden cost, ~650 us total est.):
//  - uint4 (bf16x8) LDS staging; Q/K rows padded to 65 uint4 (QK-phase row
//    reads land on 8 distinct banks, conflict-free); V unpadded (PV reads are
//    stride-1 b128, conflict-free).
//  - bf16 unpack via bit ops (x<<16 / x&0xFFFF0000), 1 unpack + 1 fma per elem.
//  - PV: thread (head hh, c) accumulates d = c*8..c*8+7 and 256+c*8.. (two
//    conflict-free column groups), uint4 stores.
// GEMM (256x256 8-phase) left untouched: at K=512 (8 K-tiles) it is capped by
// register pressure (252 regs/thread -> 1 block/CU) + prologue/tail fraction;
// ~140 us/chunk, MfmaUtil 31%.

typedef unsigned short u16;
typedef unsigned int u32;
typedef __bf16 bf16x8 __attribute__((ext_vector_type(8)));
typedef float f32x4 __attribute__((ext_vector_type(4)));

#define DEVI __device__ __forceinline__

DEVI float b2f(u16 u) {
    union { u32 i; float f; } c; c.i = ((u32)u) << 16; return c.f;
}
DEVI u16 f2b(float f) {  // RNE
    union { float f; u32 i; } c; c.f = f;
    return (u16)((c.i + 0x7FFFu + ((c.i >> 16) & 1u)) >> 16);
}
DEVI float asf(u32 x) { union { u32 i; float f; } c; c.i = x; return c.f; }

DEVI void async16(const u16* g, u16* l) {
    __builtin_amdgcn_global_load_lds(
        (const __attribute__((address_space(1))) u32*)g,
        (__attribute__((address_space(3))) u32*)l, 16, 0, 0);
}

// ---------------- prep kernels ----------------

__global__ __launch_bounds__(256) void cvt3_bf16(
    const float* __restrict__ a, const float* __restrict__ b,
    const float* __restrict__ c, u16* __restrict__ out, long ostride) {
    const float* in = (blockIdx.z == 0) ? a : (blockIdx.z == 1) ? b : c;
    u16* o = out + (long)blockIdx.z * ostride;
    const int i = blockIdx.x * 256 + threadIdx.x;
    const float4 x = ((const float4*)in)[2 * i];
    const float4 y = ((const float4*)in)[2 * i + 1];
    union { u16 u[8]; uint4 v; } r;
    r.u[0] = f2b(x.x); r.u[1] = f2b(x.y); r.u[2] = f2b(x.z); r.u[3] = f2b(x.w);
    r.u[4] = f2b(y.x); r.u[5] = f2b(y.y); r.u[6] = f2b(y.z); r.u[7] = f2b(y.w);
    ((uint4*)o)[i] = r.v;
}

__global__ void transpose_cvt(const float* __restrict__ in, u16* __restrict__ out,
                              int R, int C) {
    __shared__ float tile[32][33];
    const int c0 = blockIdx.x * 32, r0 = blockIdx.y * 32;
    const int x = threadIdx.x, y = threadIdx.y;
#pragma unroll
    for (int i = 0; i < 4; ++i) {
        const int r = y + i * 8;
        tile[x][r] = in[(long)(r0 + r) * C + c0 + x];
    }
    __syncthreads();
#pragma unroll
    for (int i = 0; i < 4; ++i) {
        const int c = y + i * 8;
        out[(long)(c0 + c) * R + r0 + x] = f2b(tile[c][x]);
    }
}

// ---------------- GEMM: C[M][N] = A[M][K] * BT[N][K]^T (+bias if F32OUT) -------
// 256x256 tile, 8-phase schedule. K multiple of 128 (NT even, >= 4).

#define VM4 asm volatile("s_waitcnt vmcnt(4)" ::: "memory")
#define VM0 asm volatile("s_waitcnt vmcnt(0)" ::: "memory")
#define LGKM0 asm volatile("s_waitcnt lgkmcnt(0)" ::: "memory")
#define NOOP ((void)0)

#define STAGE_A(t, h)                                                     \
    do {                                                                  \
        const u16* _s = pA + (long)(h) * 128 * K + (long)(t) * 64;        \
        u16* _d = As + (((t) & 1) * 16384) + (h) * 8192 + wave * 512;     \
        async16(_s, _d);                                                  \
        async16(_s + 64 * (long)K, _d + 4096);                            \
    } while (0)

#define STAGE_B(t, h)                                                     \
    do {                                                                  \
        const u16* _s = pB + (long)(h) * 128 * K + (long)(t) * 64;        \
        u16* _d = Bs + (((t) & 1) * 16384) + (h) * 8192 + wave * 512;     \
        async16(_s, _d);                                                  \
        async16(_s + 64 * (long)K, _d + 4096);                            \
    } while (0)

#define PHASE(c, P, STG, VW)                                                   \
    {                                                                          \
        const u16* _sA = As + (c) * 16384;                                     \
        const u16* _sB = Bs + (c) * 16384;                                     \
        bf16x8 a00 = *(const bf16x8*)(_sA + arow_u + (2 * (P)) * 1024 + s0);   \
        bf16x8 a01 = *(const bf16x8*)(_sA + arow_u + (2 * (P)) * 1024 + s1);   \
        bf16x8 a10 = *(const bf16x8*)(_sA + arow_u + (2 * (P) + 1) * 1024 + s0); \
        bf16x8 a11 = *(const bf16x8*)(_sA + arow_u + (2 * (P) + 1) * 1024 + s1); \
        if ((P) == 0) {                                                        \
            _Pragma("unroll") for (int n = 0; n < 4; ++n) {                    \
                bfr[n][0] = *(const bf16x8*)(_sB + brow_u + n * 1024 + s0);    \
                bfr[n][1] = *(const bf16x8*)(_sB + brow_u + n * 1024 + s1);    \
            }                                                                  \
        }                                                                      \
        STG;                                                                   \
        __builtin_amdgcn_s_barrier();                                          \
        LGKM0;                                                                 \
        __builtin_amdgcn_s_setprio(1);                                         \
        _Pragma("unroll") for (int n = 0; n < 4; ++n) {                        \
            acc[2 * (P)][n] = __builtin_amdgcn_mfma_f32_16x16x32_bf16(         \
                a00, bfr[n][0], acc[2 * (P)][n], 0, 0, 0);                     \
            acc[2 * (P)][n] = __builtin_amdgcn_mfma_f32_16x16x32_bf16(         \
                a01, bfr[n][1], acc[2 * (P)][n], 0, 0, 0);                     \
            acc[2 * (P) + 1][n] = __builtin_amdgcn_mfma_f32_16x16x32_bf16(     \
                a10, bfr[n][0], acc[2 * (P) + 1][n], 0, 0, 0);                 \
            acc[2 * (P) + 1][n] = __builtin_amdgcn_mfma_f32_16x16x32_bf16(     \
                a11, bfr[n][1], acc[2 * (P) + 1][n], 0, 0, 0);                 \
        }                                                                      \
        __builtin_amdgcn_s_setprio(0);                                         \
        VW;                                                                    \
        __builtin_amdgcn_s_barrier();                                          \
    }

template <int F32OUT>
__global__ __launch_bounds__(512, 2) void gemm256(
    const u16* __restrict__ Ab, const u16* __restrict__ Bb,
    void* __restrict__ Cv, const float* __restrict__ bias,
    int M, int N, int K, long sAz, long sBz, long sCz) {
    __shared__ u16 As[2 * 16384];   // 2 bufs x [256 rows][64 k]
    __shared__ u16 Bs[2 * 16384];
    (void)M;
    const int tid = threadIdx.x;
    const int wave = tid >> 6, lane = tid & 63;
    const int z = blockIdx.z;
    const u16* A = Ab + (long)z * sAz;
    const u16* BT = Bb + (long)z * sBz;

    int bx, by;
    {
        const int gx = gridDim.x, nwg = gx * gridDim.y;
        const int b = blockIdx.y * gx + blockIdx.x;
        if ((nwg & 7) == 0) {
            const int cpx = nwg >> 3;
            const int w = (b & 7) * cpx + (b >> 3);
            bx = w % gx; by = w / gx;
        } else { bx = blockIdx.x; by = blockIdx.y; }
    }
    const long row0 = (long)by * 256, col0 = (long)bx * 256;

    const int mrow = lane & 15, quad = lane >> 4;
    const int wr = wave >> 2, wc = wave & 3;       // 2 x 4 wave grid
    const int s0 = ((quad ^ (mrow & 7)) << 3);
    const int s1 = (((4 | quad) ^ (mrow & 7)) << 3);
    const int arow_u = (wr * 128 + mrow) * 64;
    const int brow_u = (wc * 64 + mrow) * 64;

    const int sr = tid >> 3;
    const int skg = ((tid & 7) ^ (sr & 7)) << 3;
    const u16* pA = A + (row0 + sr) * (long)K + skg;
    const u16* pB = BT + (col0 + sr) * (long)K + skg;

    f32x4 acc[8][4] = {};
    bf16x8 bfr[4][2];

    const int NT = K >> 6;   // even, >= 4
    const int NI = NT >> 1;

    STAGE_A(0, 0); STAGE_A(0, 1); STAGE_B(0, 0); STAGE_B(0, 1);
    STAGE_B(1, 0); STAGE_B(1, 1);
    VM4;
    __builtin_amdgcn_s_barrier();

#pragma unroll 1
    for (int it = 0; it < NI - 1; ++it) {
        const int t1 = 2 * it + 1;
        PHASE(0, 0, STAGE_A(t1, 0), NOOP);
        PHASE(0, 1, STAGE_A(t1, 1), NOOP);
        PHASE(0, 2, STAGE_B(t1 + 1, 0), NOOP);
        PHASE(0, 3, STAGE_B(t1 + 1, 1), VM4);
        PHASE(1, 0, STAGE_A(t1 + 1, 0), NOOP);
        PHASE(1, 1, STAGE_A(t1 + 1, 1), NOOP);
        PHASE(1, 2, STAGE_B(t1 + 2, 0), NOOP);
        PHASE(1, 3, STAGE_B(t1 + 2, 1), VM4);
    }
    {
        const int tl = NT - 1;
        PHASE(0, 0, STAGE_A(tl, 0), NOOP);
        PHASE(0, 1, STAGE_A(tl, 1), NOOP);
        PHASE(0, 2, NOOP, NOOP);
        PHASE(0, 3, NOOP, VM0);
        PHASE(1, 0, NOOP, NOOP);
        PHASE(1, 1, NOOP, NOOP);
        PHASE(1, 2, NOOP, NOOP);
        PHASE(1, 3, NOOP, NOOP);
    }

    const long wrow = row0 + wr * 128;
    const long wcol = col0 + wc * 64;
    if (F32OUT) {
        float* C = (float*)Cv + (long)z * sCz;
        float bv[4];
#pragma unroll
        for (int n = 0; n < 4; ++n) bv[n] = bias[wcol + n * 16 + mrow];
#pragma unroll
        for (int m = 0; m < 8; ++m) {
            const long r = wrow + m * 16 + quad * 4;
#pragma unroll
            for (int n = 0; n < 4; ++n) {
                const long c = wcol + n * 16 + mrow;
#pragma unroll
                for (int rr = 0; rr < 4; ++rr)
                    C[(r + rr) * (long)N + c] = acc[m][n][rr] + bv[n];
            }
        }
    } else {
        u16* C = (u16*)Cv + (long)z * sCz;
#pragma unroll
        for (int m = 0; m < 8; ++m) {
            const long r = wrow + m * 16 + quad * 4;
#pragma unroll
            for (int n = 0; n < 4; ++n) {
                const long c = wcol + n * 16 + mrow;
#pragma unroll
                for (int rr = 0; rr < 4; ++rr)
                    C[(r + rr) * (long)N + c] = f2b(acc[m][n][rr]);
            }
        }
    }
}

#undef PHASE
#undef STAGE_A
#undef STAGE_B

// ---------------- per-token attention over heads (vectorized) ----------------
// one block (256 thr) per token. Q,K rows padded (65 uint4) so QK-phase row
// reads are conflict-free; V unpadded (stride-1 PV reads). All LDS traffic is
// b128; bf16 unpack via bit ops.

DEVI float dot8(uint4 a, uint4 b) {
    const u32* pa = (const u32*)&a;
    const u32* pb = (const u32*)&b;
    float s = 0.f;
#pragma unroll
    for (int w = 0; w < 4; ++w) {
        s = fmaf(asf(pa[w] << 16), asf(pb[w] << 16), s);
        s = fmaf(asf(pa[w] & 0xFFFF0000u), asf(pb[w] & 0xFFFF0000u), s);
    }
    return s;
}

DEVI void acc8(float* o, uint4 v, float p) {
    const u32* pv = (const u32*)&v;
#pragma unroll
    for (int w = 0; w < 4; ++w) {
        o[2 * w]     = fmaf(p, asf(pv[w] << 16), o[2 * w]);
        o[2 * w + 1] = fmaf(p, asf(pv[w] & 0xFFFF0000u), o[2 * w + 1]);
    }
}

__global__ __launch_bounds__(256) void attn_kernel(
    const u16* __restrict__ Qg, const u16* __restrict__ Kg,
    const u16* __restrict__ Vg, u16* __restrict__ Og) {
    __shared__ uint4 sQ[8 * 65];   // padded: row stride 65 uint4
    __shared__ uint4 sK[8 * 65];
    __shared__ uint4 sV[512];      // unpadded: 8 x 64
    __shared__ float part[4][64];
    __shared__ float logitS[64];
    __shared__ float probS[64];
    const int t = threadIdx.x;
    const long base = (long)blockIdx.x * 4096;

    const uint4* q4 = (const uint4*)(Qg + base);
    const uint4* k4 = (const uint4*)(Kg + base);
    const uint4* v4 = (const uint4*)(Vg + base);
    {
        const int r0 = t >> 6, c0 = t & 63;
        sQ[r0 * 65 + c0] = q4[t];
        sK[r0 * 65 + c0] = k4[t];
        const int r1 = r0 + 4;
        sQ[r1 * 65 + c0] = q4[t + 256];
        sK[r1 * 65 + c0] = k4[t + 256];
        sV[t] = v4[t];
        sV[t + 256] = v4[t + 256];
    }
    __syncthreads();

    {   // logits: pair (h,g) x 4 chunks of 128 d (16 uint4 each)
        const int pr = t & 63, ch = t >> 6;
        const int h = pr >> 3, g = pr & 7;
        const uint4* qp = sQ + h * 65 + ch * 16;
        const uint4* kp = sK + g * 65 + ch * 16;
        float s = 0.f;
#pragma unroll
        for (int i = 0; i < 16; ++i) s += dot8(qp[i], kp[i]);
        part[ch][pr] = s;
    }
    __syncthreads();
    if (t < 64) logitS[t] = part[0][t] + part[1][t] + part[2][t] + part[3][t];
    __syncthreads();
    if (t < 8) {   // softmax row h=t over g
        float m = logitS[t * 8];
#pragma unroll
        for (int g = 1; g < 8; ++g) m = fmaxf(m, logitS[t * 8 + g]);
        float e[8], sum = 0.f;
#pragma unroll
        for (int g = 0; g < 8; ++g) { e[g] = __expf(logitS[t * 8 + g] - m); sum += e[g]; }
        const float inv = 1.f / sum;
#pragma unroll
        for (int g = 0; g < 8; ++g) probS[t * 8 + g] = e[g] * inv;
    }
    __syncthreads();

    // PV: thread (head hh = t>>5, c = t&31) accumulates d = c*8..+7 and
    // d = 256 + c*8..+7 (per-instr V reads are 32 consecutive uint4 -> free)
    const int hh = t >> 5, c = t & 31;
    float p[8];
#pragma unroll
    for (int g = 0; g < 8; ++g) p[g] = probS[hh * 8 + g];
    float o0[8], o1[8];
#pragma unroll
    for (int j = 0; j < 8; ++j) { o0[j] = 0.f; o1[j] = 0.f; }
#pragma unroll
    for (int g = 0; g < 8; ++g) {
        const uint4 va = sV[g * 64 + c];
        const uint4 vb = sV[g * 64 + 32 + c];
        acc8(o0, va, p[g]);
        acc8(o1, vb, p[g]);
    }
    union { u16 u[8]; uint4 v; } ob;
#pragma unroll
    for (int j = 0; j < 8; ++j) ob.u[j] = f2b(o0[j]);
    *(uint4*)(Og + base + hh * 512 + c * 8) = ob.v;
#pragma unroll
    for (int j = 0; j < 8; ++j) ob.u[j] = f2b(o1[j]);
    *(uint4*)(Og + base + hh * 512 + 256 + c * 8) = ob.v;
}

// ---------------- launch ----------------

extern "C" void kernel_launch(void* const* d_in, const int* in_sizes, int n_in,
                              void* d_out, int out_size, void* d_ws, size_t ws_size,
                              hipStream_t stream) {
    const float* Xq = (const float*)d_in[0];
    const float* Xk = (const float*)d_in[1];
    const float* Xv = (const float*)d_in[2];
    const float* Wq = (const float*)d_in[3];
    const float* Wk = (const float*)d_in[4];
    const float* Wv = (const float*)d_in[5];
    const float* Wo = (const float*)d_in[6];
    const float* bo = (const float*)d_in[7];

    const int N = 32768;
    const size_t W = 16777216ull;      // transposed weights
    const size_t AO = 268435456ull;    // full-N attn_out (Plan A)

    int McA = 0;
    for (int m = 8192; m >= 1024; m >>= 1)
        if (W + AO + (size_t)m * 27648ull <= ws_size) { McA = m; break; }

    char* ws = (char*)d_ws;
    u16* WqT = (u16*)(ws);                    // [4096][512] x3 contiguous
    u16* WoT = (u16*)(ws + 12582912ull);      // [512][4096]

    dim3 tb(32, 8);
    transpose_cvt<<<dim3(128, 16), tb, 0, stream>>>(Wq, WqT, 512, 4096);
    transpose_cvt<<<dim3(128, 16), tb, 0, stream>>>(Wk, WqT + 2097152, 512, 4096);
    transpose_cvt<<<dim3(128, 16), tb, 0, stream>>>(Wv, WqT + 4194304, 512, 4096);
    transpose_cvt<<<dim3(16, 128), tb, 0, stream>>>(Wo, WoT, 4096, 512);

    if (McA) {
        // ---- Plan A ----
        const int Mc = McA;
        u16* Ao  = (u16*)(ws + W);
        u16* Xb  = (u16*)(ws + W + AO);           // 3x [Mc][512]
        u16* Qc  = Xb + (size_t)3 * Mc * 512;     // 3x [Mc][4096]
        u16* Kc  = Qc + (size_t)Mc * 4096;
        u16* Vc  = Kc + (size_t)Mc * 4096;
        const dim3 gProj(16, Mc / 256, 3);
        for (int m0 = 0; m0 < N; m0 += Mc) {
            const long xoff = (long)m0 * 512;
            cvt3_bf16<<<dim3(Mc / 4, 1, 3), 256, 0, stream>>>(
                Xq + xoff, Xk + xoff, Xv + xoff, Xb, (long)Mc * 512);
            gemm256<0><<<gProj, 512, 0, stream>>>(Xb, WqT, Qc, nullptr,
                                                  Mc, 4096, 512,
                                                  (long)Mc * 512, 2097152L,
                                                  (long)Mc * 4096);
            attn_kernel<<<Mc, 256, 0, stream>>>(Qc, Kc, Vc, Ao + (long)m0 * 4096);
        }
        gemm256<1><<<dim3(2, 128, 1), 512, 0, stream>>>(
            Ao, WoT, d_out, bo, N, 512, 4096, 0L, 0L, 0L);
    } else {
        // ---- Plan B (streaming) ----
        int Mc = 8192;
        while (Mc > 256 && W + (size_t)Mc * 27648ull > ws_size) Mc >>= 1;
        if (W + (size_t)Mc * 27648ull > ws_size) return;
        u16* Xb = (u16*)(ws + W);
        u16* Qc = Xb + (size_t)3 * Mc * 512;
        u16* Kc = Qc + (size_t)Mc * 4096;
        u16* Vc = Kc + (size_t)Mc * 4096;
        const dim3 gProj(16, Mc / 256, 3);
        const dim3 gOut(2, Mc / 256, 1);
        for (int m0 = 0; m0 < N; m0 += Mc) {
            const long xoff = (long)m0 * 512;
            cvt3_bf16<<<dim3(Mc / 4, 1, 3), 256, 0, stream>>>(
                Xq + xoff, Xk + xoff, Xv + xoff, Xb, (long)Mc * 512);
            gemm256<0><<<gProj, 512, 0, stream>>>(Xb, WqT, Qc, nullptr,
                                                  Mc, 4096, 512,
                                                  (long)Mc * 512, 2097152L,
                                                  (long)Mc * 4096);
            attn_kernel<<<Mc, 256, 0, stream>>>(Qc, Kc, Vc, Qc);
            gemm256<1><<<gOut, 512, 0, stream>>>(Qc, WoT, (float*)d_out + xoff, bo,
                                                 Mc, 512, 4096, 0L, 0L, 0L);
        }
    }
}